// Round 1
// baseline (713.665 us; speedup 1.0000x reference)
//
#include <hip/hip_runtime.h>
#include <cmath>

#define BATCH 64
#define NCTX 2048
#define DIM 1024
#define CHUNKS 16
#define ROWS_PER_CHUNK (NCTX / CHUNKS)     // 128
#define ROWS_PER_WAVE (ROWS_PER_CHUNK / 4) // 32

// ---------------- Phase 1: flash-style scores + online softmax partials ---------------
// grid = BATCH*CHUNKS blocks, 256 threads (4 waves). Each wave does 32 context rows.
__global__ __launch_bounds__(256) void attn_phase1(
    const float* __restrict__ q,     // [B, 1, D]
    const float* __restrict__ ctx,   // [B, N, D]
    float* __restrict__ scores,      // [B, N]      (raw logits)
    float* __restrict__ part_m,      // [B, CHUNKS]
    float* __restrict__ part_l,      // [B, CHUNKS]
    float* __restrict__ part_o)      // [B, CHUNKS, D]
{
    const int blk  = blockIdx.x;
    const int b    = blk / CHUNKS;
    const int c    = blk % CHUNKS;
    const int tid  = threadIdx.x;
    const int wave = tid >> 6;
    const int lane = tid & 63;

    // q fragment: lane covers elements lane*4 + 256*j + {0..3}, j=0..3
    float4 qf[4];
    const float* qb = q + (size_t)b * DIM;
    #pragma unroll
    for (int j = 0; j < 4; ++j)
        qf[j] = *reinterpret_cast<const float4*>(qb + lane * 4 + 256 * j);

    float m = -INFINITY, l = 0.f;
    float4 o[4];
    #pragma unroll
    for (int j = 0; j < 4; ++j) o[j] = make_float4(0.f, 0.f, 0.f, 0.f);

    const int row0 = c * ROWS_PER_CHUNK + wave * ROWS_PER_WAVE;
    const float* cb = ctx + (size_t)b * NCTX * DIM;

    for (int i = 0; i < ROWS_PER_WAVE; ++i) {
        const int row = row0 + i;
        const float* cr = cb + (size_t)row * DIM + lane * 4;
        float4 cf[4];
        #pragma unroll
        for (int j = 0; j < 4; ++j)
            cf[j] = *reinterpret_cast<const float4*>(cr + 256 * j);

        float s = 0.f;
        #pragma unroll
        for (int j = 0; j < 4; ++j) {
            s += qf[j].x * cf[j].x;
            s += qf[j].y * cf[j].y;
            s += qf[j].z * cf[j].z;
            s += qf[j].w * cf[j].w;
        }
        // wave-wide butterfly reduce (64 lanes)
        #pragma unroll
        for (int off = 32; off >= 1; off >>= 1)
            s += __shfl_xor(s, off, 64);

        if (lane == 0) scores[(size_t)b * NCTX + row] = s;

        const float m_new = fmaxf(m, s);
        const float alpha = __expf(m - m_new);
        const float p     = __expf(s - m_new);
        l = l * alpha + p;
        #pragma unroll
        for (int j = 0; j < 4; ++j) {
            o[j].x = o[j].x * alpha + p * cf[j].x;
            o[j].y = o[j].y * alpha + p * cf[j].y;
            o[j].z = o[j].z * alpha + p * cf[j].z;
            o[j].w = o[j].w * alpha + p * cf[j].w;
        }
        m = m_new;
    }

    // ---- combine the 4 waves of this block ----
    __shared__ float wm[4], wl[4];
    __shared__ float o_lds[4 * DIM];
    if (lane == 0) { wm[wave] = m; wl[wave] = l; }
    __syncthreads();

    const float Mb = fmaxf(fmaxf(wm[0], wm[1]), fmaxf(wm[2], wm[3]));
    float Lb = 0.f;
    #pragma unroll
    for (int w = 0; w < 4; ++w) Lb += wl[w] * __expf(wm[w] - Mb);

    const float aw = __expf(m - Mb);
    #pragma unroll
    for (int j = 0; j < 4; ++j) {
        float4 t = o[j];
        t.x *= aw; t.y *= aw; t.z *= aw; t.w *= aw;
        *reinterpret_cast<float4*>(&o_lds[wave * DIM + lane * 4 + 256 * j]) = t;
    }
    __syncthreads();

    {
        const int e = tid * 4;
        float4 s0 = *reinterpret_cast<const float4*>(&o_lds[0 * DIM + e]);
        float4 s1 = *reinterpret_cast<const float4*>(&o_lds[1 * DIM + e]);
        float4 s2 = *reinterpret_cast<const float4*>(&o_lds[2 * DIM + e]);
        float4 s3 = *reinterpret_cast<const float4*>(&o_lds[3 * DIM + e]);
        float4 r;
        r.x = s0.x + s1.x + s2.x + s3.x;
        r.y = s0.y + s1.y + s2.y + s3.y;
        r.z = s0.z + s1.z + s2.z + s3.z;
        r.w = s0.w + s1.w + s2.w + s3.w;
        *reinterpret_cast<float4*>(&part_o[((size_t)b * CHUNKS + c) * DIM + e]) = r;
    }
    if (tid == 0) {
        part_m[b * CHUNKS + c] = Mb;
        part_l[b * CHUNKS + c] = Lb;
    }
}

// ---------------- Phase 2: combine chunk partials -> mix; write attn -----------------
// grid = BATCH blocks, 256 threads
__global__ __launch_bounds__(256) void attn_phase2(
    const float* __restrict__ scores,
    const float* __restrict__ part_m,
    const float* __restrict__ part_l,
    const float* __restrict__ part_o,
    float* __restrict__ mix,        // [B, D] workspace
    float* __restrict__ attn_out)   // d_out + B*D, [B, N]
{
    const int b = blockIdx.x;
    const int tid = threadIdx.x;

    float M = -INFINITY;
    #pragma unroll
    for (int i = 0; i < CHUNKS; ++i) M = fmaxf(M, part_m[b * CHUNKS + i]);

    float w[CHUNKS];
    float L = 0.f;
    #pragma unroll
    for (int i = 0; i < CHUNKS; ++i) {
        w[i] = __expf(part_m[b * CHUNKS + i] - M);
        L += part_l[b * CHUNKS + i] * w[i];
    }
    const float invL = 1.f / L;

    const int e = tid * 4;
    float4 acc = make_float4(0.f, 0.f, 0.f, 0.f);
    #pragma unroll
    for (int i = 0; i < CHUNKS; ++i) {
        float4 t = *reinterpret_cast<const float4*>(
            &part_o[((size_t)b * CHUNKS + i) * DIM + e]);
        acc.x += t.x * w[i];
        acc.y += t.y * w[i];
        acc.z += t.z * w[i];
        acc.w += t.w * w[i];
    }
    acc.x *= invL; acc.y *= invL; acc.z *= invL; acc.w *= invL;
    *reinterpret_cast<float4*>(&mix[(size_t)b * DIM + e]) = acc;

    for (int n = tid; n < NCTX; n += 256)
        attn_out[(size_t)b * NCTX + n] =
            __expf(scores[(size_t)b * NCTX + n] - M) * invL;
}

// ---------------- Phase 3: out = tanh([mix, q] @ W^T + bias) --------------------------
// grid = (D/32) * (B/8) = 256 blocks, 256 threads. LDS: combined[8][2048] = 64 KB.
#define BT 8
#define DT 32
__global__ __launch_bounds__(256) void attn_phase3(
    const float* __restrict__ mix,   // [B, D]
    const float* __restrict__ q,     // [B, 1, D]
    const float* __restrict__ W,     // [D, 2D]
    const float* __restrict__ bias,  // [D]
    float* __restrict__ out)         // d_out, [B, D]
{
    const int d_chunk = blockIdx.x % (DIM / DT);
    const int b_chunk = blockIdx.x / (DIM / DT);
    const int d0 = d_chunk * DT;
    const int b0 = b_chunk * BT;
    const int tid  = threadIdx.x;
    const int wave = tid >> 6;
    const int lane = tid & 63;

    __shared__ float comb[BT * 2 * DIM];   // 8 * 2048 floats = 64 KB
    for (int i = tid; i < BT * 2 * DIM; i += 256) {
        const int bl = i >> 11;          // / 2048
        const int e  = i & 2047;
        comb[i] = (e < DIM) ? mix[(size_t)(b0 + bl) * DIM + e]
                            : q[(size_t)(b0 + bl) * DIM + (e - DIM)];
    }
    __syncthreads();

    const int d_base = d0 + wave * (DT / 4);   // 8 d's per wave
    #pragma unroll
    for (int g = 0; g < 2; ++g) {
        const int dg = d_base + g * 4;
        float acc[4][BT];
        #pragma unroll
        for (int di = 0; di < 4; ++di)
            #pragma unroll
            for (int bl = 0; bl < BT; ++bl) acc[di][bl] = 0.f;

        for (int kk = 0; kk < 2 * DIM; kk += 256) {
            float4 wv[4];
            #pragma unroll
            for (int di = 0; di < 4; ++di)
                wv[di] = *reinterpret_cast<const float4*>(
                    W + (size_t)(dg + di) * (2 * DIM) + kk + lane * 4);
            #pragma unroll
            for (int bl = 0; bl < BT; ++bl) {
                float4 cv = *reinterpret_cast<const float4*>(
                    &comb[bl * 2 * DIM + kk + lane * 4]);
                #pragma unroll
                for (int di = 0; di < 4; ++di) {
                    acc[di][bl] += wv[di].x * cv.x;
                    acc[di][bl] += wv[di].y * cv.y;
                    acc[di][bl] += wv[di].z * cv.z;
                    acc[di][bl] += wv[di].w * cv.w;
                }
            }
        }

        float myval = 0.f;
        #pragma unroll
        for (int di = 0; di < 4; ++di) {
            #pragma unroll
            for (int bl = 0; bl < BT; ++bl) {
                float v = acc[di][bl];
                #pragma unroll
                for (int off = 32; off >= 1; off >>= 1)
                    v += __shfl_xor(v, off, 64);
                if (lane == di * BT + bl) myval = v;
            }
        }
        if (lane < 32) {
            const int di = lane >> 3;
            const int bl = lane & 7;
            const int d  = dg + di;
            out[(size_t)(b0 + bl) * DIM + d] = tanhf(myval + bias[d]);
        }
    }
}

extern "C" void kernel_launch(void* const* d_in, const int* in_sizes, int n_in,
                              void* d_out, int out_size, void* d_ws, size_t ws_size,
                              hipStream_t stream) {
    const float* q    = (const float*)d_in[0];   // output, [B,1,D]
    const float* ctx  = (const float*)d_in[1];   // context, [B,N,D]
    const float* W    = (const float*)d_in[2];   // W_out, [D, 2D]
    const float* bias = (const float*)d_in[3];   // b_out, [D]

    float* out_main = (float*)d_out;                         // [B, D]
    float* attn_out = (float*)d_out + (size_t)BATCH * DIM;   // [B, N]

    // workspace layout (floats): scores | part_m | part_l | part_o | mix  (~5 MB)
    float* ws      = (float*)d_ws;
    float* scores  = ws;                                   // B*N      = 131072
    float* part_m  = scores + (size_t)BATCH * NCTX;        // B*CHUNKS = 1024
    float* part_l  = part_m + BATCH * CHUNKS;              // 1024
    float* part_o  = part_l + BATCH * CHUNKS;              // B*CHUNKS*D = 1048576
    float* mix     = part_o + (size_t)BATCH * CHUNKS * DIM; // B*D = 65536

    attn_phase1<<<BATCH * CHUNKS, 256, 0, stream>>>(q, ctx, scores,
                                                    part_m, part_l, part_o);
    attn_phase2<<<BATCH, 256, 0, stream>>>(scores, part_m, part_l, part_o,
                                           mix, attn_out);
    attn_phase3<<<(DIM / DT) * (BATCH / BT), 256, 0, stream>>>(mix, q, W, bias,
                                                               out_main);
}

// Round 2
// 711.175 us; speedup vs baseline: 1.0035x; 1.0035x over previous
//
#include <hip/hip_runtime.h>
#include <cmath>

#define BATCH 64
#define NCTX 2048
#define DIM 1024
#define CHUNKS 32
#define ROWS_PER_CHUNK (NCTX / CHUNKS)     // 64
#define ROWS_PER_WAVE (ROWS_PER_CHUNK / 4) // 16

// ---------------- Phase 1: flash-style scores + online softmax partials ---------------
// grid = BATCH*CHUNKS = 2048 blocks, 256 threads (4 waves). Each wave: 16 rows, 2/iter.
__global__ __launch_bounds__(256) void attn_phase1(
    const float* __restrict__ q,     // [B, 1, D]
    const float* __restrict__ ctx,   // [B, N, D]
    float* __restrict__ scores,      // [B, N]      (raw logits)
    float* __restrict__ part_m,      // [B, CHUNKS]
    float* __restrict__ part_l,      // [B, CHUNKS]
    float* __restrict__ part_o)      // [B, CHUNKS, D]
{
    const int blk  = blockIdx.x;
    const int b    = blk / CHUNKS;
    const int c    = blk % CHUNKS;
    const int tid  = threadIdx.x;
    const int wave = tid >> 6;
    const int lane = tid & 63;

    // q fragment: lane covers elements lane*4 + 256*j + {0..3}, j=0..3
    float4 qf[4];
    const float* qb = q + (size_t)b * DIM;
    #pragma unroll
    for (int j = 0; j < 4; ++j)
        qf[j] = *reinterpret_cast<const float4*>(qb + lane * 4 + 256 * j);

    float m = -INFINITY, l = 0.f;
    float4 o[4];
    #pragma unroll
    for (int j = 0; j < 4; ++j) o[j] = make_float4(0.f, 0.f, 0.f, 0.f);

    const int row0 = c * ROWS_PER_CHUNK + wave * ROWS_PER_WAVE;
    const float* cb = ctx + (size_t)b * NCTX * DIM;
    float* sc = scores + (size_t)b * NCTX;

    for (int i = 0; i < ROWS_PER_WAVE; i += 2) {
        const int rowA = row0 + i;
        const int rowB = rowA + 1;
        const float* crA = cb + (size_t)rowA * DIM + lane * 4;
        const float* crB = cb + (size_t)rowB * DIM + lane * 4;
        float4 cfA[4], cfB[4];
        #pragma unroll
        for (int j = 0; j < 4; ++j) {
            cfA[j] = *reinterpret_cast<const float4*>(crA + 256 * j);
            cfB[j] = *reinterpret_cast<const float4*>(crB + 256 * j);
        }

        // dots (tree-combined to shorten the dependent chain)
        float dA[4], dB[4];
        #pragma unroll
        for (int j = 0; j < 4; ++j) {
            dA[j] = qf[j].x * cfA[j].x + qf[j].y * cfA[j].y
                  + qf[j].z * cfA[j].z + qf[j].w * cfA[j].w;
            dB[j] = qf[j].x * cfB[j].x + qf[j].y * cfB[j].y
                  + qf[j].z * cfB[j].z + qf[j].w * cfB[j].w;
        }
        float s0 = (dA[0] + dA[1]) + (dA[2] + dA[3]);
        float s1 = (dB[0] + dB[1]) + (dB[2] + dB[3]);

        // two independent 64-lane butterflies (latency overlaps)
        #pragma unroll
        for (int off = 32; off >= 1; off >>= 1) {
            s0 += __shfl_xor(s0, off, 64);
            s1 += __shfl_xor(s1, off, 64);
        }

        if (lane < 2) sc[rowA + lane] = lane ? s1 : s0;

        // wave-uniform rare rescale (s0/s1 uniform after full butterfly)
        const float m_new = fmaxf(m, fmaxf(s0, s1));
        if (m_new > m) {
            const float a = __expf(m - m_new);
            l *= a;
            #pragma unroll
            for (int j = 0; j < 4; ++j) {
                o[j].x *= a; o[j].y *= a; o[j].z *= a; o[j].w *= a;
            }
            m = m_new;
        }
        const float p0 = __expf(s0 - m);
        const float p1 = __expf(s1 - m);
        l += p0 + p1;
        #pragma unroll
        for (int j = 0; j < 4; ++j) {
            o[j].x += p0 * cfA[j].x + p1 * cfB[j].x;
            o[j].y += p0 * cfA[j].y + p1 * cfB[j].y;
            o[j].z += p0 * cfA[j].z + p1 * cfB[j].z;
            o[j].w += p0 * cfA[j].w + p1 * cfB[j].w;
        }
    }

    // ---- combine the 4 waves of this block ----
    __shared__ float wm[4], wl[4];
    __shared__ float o_lds[4 * DIM];
    if (lane == 0) { wm[wave] = m; wl[wave] = l; }
    __syncthreads();

    const float Mb = fmaxf(fmaxf(wm[0], wm[1]), fmaxf(wm[2], wm[3]));
    float Lb = 0.f;
    #pragma unroll
    for (int w = 0; w < 4; ++w) Lb += wl[w] * __expf(wm[w] - Mb);

    const float aw = __expf(m - Mb);
    #pragma unroll
    for (int j = 0; j < 4; ++j) {
        float4 t = o[j];
        t.x *= aw; t.y *= aw; t.z *= aw; t.w *= aw;
        *reinterpret_cast<float4*>(&o_lds[wave * DIM + lane * 4 + 256 * j]) = t;
    }
    __syncthreads();

    {
        const int e = tid * 4;
        float4 s0 = *reinterpret_cast<const float4*>(&o_lds[0 * DIM + e]);
        float4 s1 = *reinterpret_cast<const float4*>(&o_lds[1 * DIM + e]);
        float4 s2 = *reinterpret_cast<const float4*>(&o_lds[2 * DIM + e]);
        float4 s3 = *reinterpret_cast<const float4*>(&o_lds[3 * DIM + e]);
        float4 r;
        r.x = s0.x + s1.x + s2.x + s3.x;
        r.y = s0.y + s1.y + s2.y + s3.y;
        r.z = s0.z + s1.z + s2.z + s3.z;
        r.w = s0.w + s1.w + s2.w + s3.w;
        *reinterpret_cast<float4*>(&part_o[((size_t)b * CHUNKS + c) * DIM + e]) = r;
    }
    if (tid == 0) {
        part_m[b * CHUNKS + c] = Mb;
        part_l[b * CHUNKS + c] = Lb;
    }
}

// ---------------- Phase 2: combine chunk partials -> mix; write attn -----------------
// grid = BATCH blocks, 256 threads
__global__ __launch_bounds__(256) void attn_phase2(
    const float* __restrict__ scores,
    const float* __restrict__ part_m,
    const float* __restrict__ part_l,
    const float* __restrict__ part_o,
    float* __restrict__ mix,        // [B, D] workspace
    float* __restrict__ attn_out)   // d_out + B*D, [B, N]
{
    const int b = blockIdx.x;
    const int tid = threadIdx.x;

    float M = -INFINITY;
    #pragma unroll
    for (int i = 0; i < CHUNKS; ++i) M = fmaxf(M, part_m[b * CHUNKS + i]);

    float w[CHUNKS];
    float L = 0.f;
    #pragma unroll
    for (int i = 0; i < CHUNKS; ++i) {
        w[i] = __expf(part_m[b * CHUNKS + i] - M);
        L += part_l[b * CHUNKS + i] * w[i];
    }
    const float invL = 1.f / L;

    const int e = tid * 4;
    float4 acc = make_float4(0.f, 0.f, 0.f, 0.f);
    #pragma unroll
    for (int i = 0; i < CHUNKS; ++i) {
        float4 t = *reinterpret_cast<const float4*>(
            &part_o[((size_t)b * CHUNKS + i) * DIM + e]);
        acc.x += t.x * w[i];
        acc.y += t.y * w[i];
        acc.z += t.z * w[i];
        acc.w += t.w * w[i];
    }
    acc.x *= invL; acc.y *= invL; acc.z *= invL; acc.w *= invL;
    *reinterpret_cast<float4*>(&mix[(size_t)b * DIM + e]) = acc;

    for (int n = tid; n < NCTX; n += 256)
        attn_out[(size_t)b * NCTX + n] =
            __expf(scores[(size_t)b * NCTX + n] - M) * invL;
}

// ---------------- Phase 3: out = tanh([mix, q] @ W^T + bias) --------------------------
// grid = (D/32) * (B/4) = 512 blocks, 256 threads. LDS: combined[4][2048] = 32 KB.
#define BT 4
#define DT 32
__global__ __launch_bounds__(256) void attn_phase3(
    const float* __restrict__ mix,   // [B, D]
    const float* __restrict__ q,     // [B, 1, D]
    const float* __restrict__ W,     // [D, 2D]
    const float* __restrict__ bias,  // [D]
    float* __restrict__ out)         // d_out, [B, D]
{
    const int d_chunk = blockIdx.x % (DIM / DT);
    const int b_chunk = blockIdx.x / (DIM / DT);
    const int d0 = d_chunk * DT;
    const int b0 = b_chunk * BT;
    const int tid  = threadIdx.x;
    const int wave = tid >> 6;
    const int lane = tid & 63;

    __shared__ float comb[BT * 2 * DIM];   // 4 * 2048 floats = 32 KB
    for (int i = tid; i < BT * 2 * DIM; i += 256) {
        const int bl = i >> 11;          // / 2048
        const int e  = i & 2047;
        comb[i] = (e < DIM) ? mix[(size_t)(b0 + bl) * DIM + e]
                            : q[(size_t)(b0 + bl) * DIM + (e - DIM)];
    }
    __syncthreads();

    const int d_base = d0 + wave * (DT / 4);   // 8 d's per wave
    #pragma unroll
    for (int g = 0; g < 2; ++g) {
        const int dg = d_base + g * 4;
        float acc[4][BT];
        #pragma unroll
        for (int di = 0; di < 4; ++di)
            #pragma unroll
            for (int bl = 0; bl < BT; ++bl) acc[di][bl] = 0.f;

        for (int kk = 0; kk < 2 * DIM; kk += 256) {
            float4 wv[4];
            #pragma unroll
            for (int di = 0; di < 4; ++di)
                wv[di] = *reinterpret_cast<const float4*>(
                    W + (size_t)(dg + di) * (2 * DIM) + kk + lane * 4);
            #pragma unroll
            for (int bl = 0; bl < BT; ++bl) {
                float4 cv = *reinterpret_cast<const float4*>(
                    &comb[bl * 2 * DIM + kk + lane * 4]);
                #pragma unroll
                for (int di = 0; di < 4; ++di) {
                    acc[di][bl] += wv[di].x * cv.x;
                    acc[di][bl] += wv[di].y * cv.y;
                    acc[di][bl] += wv[di].z * cv.z;
                    acc[di][bl] += wv[di].w * cv.w;
                }
            }
        }

        float myval = 0.f;
        #pragma unroll
        for (int di = 0; di < 4; ++di) {
            #pragma unroll
            for (int bl = 0; bl < BT; ++bl) {
                float v = acc[di][bl];
                #pragma unroll
                for (int off = 32; off >= 1; off >>= 1)
                    v += __shfl_xor(v, off, 64);
                if (lane == di * BT + bl) myval = v;
            }
        }
        if (lane < 16) {
            const int di = lane >> 2;
            const int bl = lane & 3;
            const int d  = dg + di;
            out[(size_t)(b0 + bl) * DIM + d] = tanhf(myval + bias[d]);
        }
    }
}

extern "C" void kernel_launch(void* const* d_in, const int* in_sizes, int n_in,
                              void* d_out, int out_size, void* d_ws, size_t ws_size,
                              hipStream_t stream) {
    const float* q    = (const float*)d_in[0];   // output, [B,1,D]
    const float* ctx  = (const float*)d_in[1];   // context, [B,N,D]
    const float* W    = (const float*)d_in[2];   // W_out, [D, 2D]
    const float* bias = (const float*)d_in[3];   // b_out, [D]

    float* out_main = (float*)d_out;                         // [B, D]
    float* attn_out = (float*)d_out + (size_t)BATCH * DIM;   // [B, N]

    // workspace layout (floats): scores | part_m | part_l | part_o | mix  (~9 MB)
    float* ws      = (float*)d_ws;
    float* scores  = ws;                                    // B*N       = 131072
    float* part_m  = scores + (size_t)BATCH * NCTX;         // B*CHUNKS  = 2048
    float* part_l  = part_m + BATCH * CHUNKS;               // 2048
    float* part_o  = part_l + BATCH * CHUNKS;               // B*CHUNKS*D = 2097152
    float* mix     = part_o + (size_t)BATCH * CHUNKS * DIM; // B*D = 65536

    attn_phase1<<<BATCH * CHUNKS, 256, 0, stream>>>(q, ctx, scores,
                                                    part_m, part_l, part_o);
    attn_phase2<<<BATCH, 256, 0, stream>>>(scores, part_m, part_l, part_o,
                                           mix, attn_out);
    attn_phase3<<<(DIM / DT) * (BATCH / BT), 256, 0, stream>>>(mix, q, W, bias,
                                                               out_main);
}

// Round 3
// 675.142 us; speedup vs baseline: 1.0571x; 1.0534x over previous
//
#include <hip/hip_runtime.h>
#include <cmath>

#define BATCH 64
#define NCTX 2048
#define DIM 1024
#define CHUNKS 16
#define ROWS_PER_CHUNK (NCTX / CHUNKS)     // 128
#define ROWS_PER_WAVE (ROWS_PER_CHUNK / 4) // 32

typedef float f4_t __attribute__((ext_vector_type(4)));

// ---------------- Phase 1: flash-style scores + online softmax partials ---------------
// grid = BATCH*CHUNKS = 1024 blocks, 256 threads (4 waves).
// Each wave: 32 rows, 4 rows/iter (16 dwordx4 loads in flight, 4 parallel butterflies).
__global__ __launch_bounds__(256) void attn_phase1(
    const float* __restrict__ q,     // [B, 1, D]
    const float* __restrict__ ctx,   // [B, N, D]
    float* __restrict__ scores,      // [B, N]      (raw logits)
    float* __restrict__ part_m,      // [B, CHUNKS]
    float* __restrict__ part_l,      // [B, CHUNKS]
    float* __restrict__ part_o)      // [B, CHUNKS, D]
{
    const int blk  = blockIdx.x;
    const int b    = blk / CHUNKS;
    const int c    = blk % CHUNKS;
    const int tid  = threadIdx.x;
    const int wave = tid >> 6;
    const int lane = tid & 63;

    // q fragment: lane covers elements lane*4 + 256*j + {0..3}, j=0..3
    f4_t qf[4];
    const float* qb = q + (size_t)b * DIM;
    #pragma unroll
    for (int j = 0; j < 4; ++j)
        qf[j] = *reinterpret_cast<const f4_t*>(qb + lane * 4 + 256 * j);

    float m = -INFINITY, l = 0.f;
    f4_t o[4];
    #pragma unroll
    for (int j = 0; j < 4; ++j) o[j] = (f4_t)(0.f);

    const int row0 = c * ROWS_PER_CHUNK + wave * ROWS_PER_WAVE;
    const float* cb = ctx + (size_t)b * NCTX * DIM;
    float* sc = scores + (size_t)b * NCTX;

    for (int i = 0; i < ROWS_PER_WAVE; i += 4) {
        f4_t cf[4][4];
        #pragma unroll
        for (int r = 0; r < 4; ++r) {
            const float* cr = cb + (size_t)(row0 + i + r) * DIM + lane * 4;
            #pragma unroll
            for (int j = 0; j < 4; ++j)
                cf[r][j] = __builtin_nontemporal_load(
                    reinterpret_cast<const f4_t*>(cr + 256 * j));
        }

        float s[4];
        #pragma unroll
        for (int r = 0; r < 4; ++r) {
            float d0 = qf[0].x * cf[r][0].x + qf[0].y * cf[r][0].y
                     + qf[0].z * cf[r][0].z + qf[0].w * cf[r][0].w;
            float d1 = qf[1].x * cf[r][1].x + qf[1].y * cf[r][1].y
                     + qf[1].z * cf[r][1].z + qf[1].w * cf[r][1].w;
            float d2 = qf[2].x * cf[r][2].x + qf[2].y * cf[r][2].y
                     + qf[2].z * cf[r][2].z + qf[2].w * cf[r][2].w;
            float d3 = qf[3].x * cf[r][3].x + qf[3].y * cf[r][3].y
                     + qf[3].z * cf[r][3].z + qf[3].w * cf[r][3].w;
            s[r] = (d0 + d1) + (d2 + d3);
        }

        // four independent 64-lane butterflies (latency overlaps 4-way)
        #pragma unroll
        for (int off = 32; off >= 1; off >>= 1) {
            s[0] += __shfl_xor(s[0], off, 64);
            s[1] += __shfl_xor(s[1], off, 64);
            s[2] += __shfl_xor(s[2], off, 64);
            s[3] += __shfl_xor(s[3], off, 64);
        }

        {
            float sv = (lane == 1) ? s[1] : (lane == 2) ? s[2]
                     : (lane == 3) ? s[3] : s[0];
            if (lane < 4) sc[row0 + i + lane] = sv;
        }

        // wave-uniform rare rescale (s[] uniform after full butterfly)
        const float mx = fmaxf(fmaxf(s[0], s[1]), fmaxf(s[2], s[3]));
        const float m_new = fmaxf(m, mx);
        if (m_new > m) {
            const float a = __expf(m - m_new);
            l *= a;
            #pragma unroll
            for (int j = 0; j < 4; ++j) o[j] *= a;
            m = m_new;
        }
        const float p0 = __expf(s[0] - m);
        const float p1 = __expf(s[1] - m);
        const float p2 = __expf(s[2] - m);
        const float p3 = __expf(s[3] - m);
        l += (p0 + p1) + (p2 + p3);
        #pragma unroll
        for (int j = 0; j < 4; ++j) {
            o[j].x += p0 * cf[0][j].x + p1 * cf[1][j].x
                    + p2 * cf[2][j].x + p3 * cf[3][j].x;
            o[j].y += p0 * cf[0][j].y + p1 * cf[1][j].y
                    + p2 * cf[2][j].y + p3 * cf[3][j].y;
            o[j].z += p0 * cf[0][j].z + p1 * cf[1][j].z
                    + p2 * cf[2][j].z + p3 * cf[3][j].z;
            o[j].w += p0 * cf[0][j].w + p1 * cf[1][j].w
                    + p2 * cf[2][j].w + p3 * cf[3][j].w;
        }
    }

    // ---- combine the 4 waves of this block ----
    __shared__ float wm[4], wl[4];
    __shared__ float o_lds[4 * DIM];
    if (lane == 0) { wm[wave] = m; wl[wave] = l; }
    __syncthreads();

    const float Mb = fmaxf(fmaxf(wm[0], wm[1]), fmaxf(wm[2], wm[3]));
    float Lb = 0.f;
    #pragma unroll
    for (int w = 0; w < 4; ++w) Lb += wl[w] * __expf(wm[w] - Mb);

    const float aw = __expf(m - Mb);
    #pragma unroll
    for (int j = 0; j < 4; ++j) {
        f4_t t = o[j] * aw;
        *reinterpret_cast<f4_t*>(&o_lds[wave * DIM + lane * 4 + 256 * j]) = t;
    }
    __syncthreads();

    {
        const int e = tid * 4;
        f4_t s0 = *reinterpret_cast<const f4_t*>(&o_lds[0 * DIM + e]);
        f4_t s1 = *reinterpret_cast<const f4_t*>(&o_lds[1 * DIM + e]);
        f4_t s2 = *reinterpret_cast<const f4_t*>(&o_lds[2 * DIM + e]);
        f4_t s3 = *reinterpret_cast<const f4_t*>(&o_lds[3 * DIM + e]);
        f4_t r = (s0 + s1) + (s2 + s3);
        *reinterpret_cast<f4_t*>(&part_o[((size_t)b * CHUNKS + c) * DIM + e]) = r;
    }
    if (tid == 0) {
        part_m[b * CHUNKS + c] = Mb;
        part_l[b * CHUNKS + c] = Lb;
    }
}

// ---------------- Phase 2: combine chunk partials -> mix; write attn -----------------
// grid = BATCH*4 = 256 blocks, 256 threads. Each block: D/4 mix elems + N/4 attn elems.
__global__ __launch_bounds__(256) void attn_phase2(
    const float* __restrict__ scores,
    const float* __restrict__ part_m,
    const float* __restrict__ part_l,
    const float* __restrict__ part_o,
    float* __restrict__ mix,        // [B, D] workspace
    float* __restrict__ attn_out)   // d_out + B*D, [B, N]
{
    const int b    = blockIdx.x >> 2;
    const int part = blockIdx.x & 3;
    const int tid  = threadIdx.x;

    float M = -INFINITY;
    #pragma unroll
    for (int i = 0; i < CHUNKS; ++i) M = fmaxf(M, part_m[b * CHUNKS + i]);

    float w[CHUNKS];
    float L = 0.f;
    #pragma unroll
    for (int i = 0; i < CHUNKS; ++i) {
        w[i] = __expf(part_m[b * CHUNKS + i] - M);
        L += part_l[b * CHUNKS + i] * w[i];
    }
    const float invL = 1.f / L;

    // mix slice: 256 consecutive elements
    {
        const int e = part * 256 + tid;
        float acc = 0.f;
        #pragma unroll
        for (int i = 0; i < CHUNKS; ++i)
            acc += part_o[((size_t)b * CHUNKS + i) * DIM + e] * w[i];
        mix[(size_t)b * DIM + e] = acc * invL;
    }

    // attn slice: 512 consecutive elements
    #pragma unroll
    for (int t = 0; t < 2; ++t) {
        const int n = part * 512 + t * 256 + tid;
        attn_out[(size_t)b * NCTX + n] =
            __expf(scores[(size_t)b * NCTX + n] - M) * invL;
    }
}

// ---------------- Phase 3: out = tanh([mix, q] @ W^T + bias) --------------------------
// grid = (D/32) * (B/4) = 512 blocks, 256 threads. LDS: combined[4][2048] = 32 KB.
#define BT 4
#define DT 32
__global__ __launch_bounds__(256) void attn_phase3(
    const float* __restrict__ mix,   // [B, D]
    const float* __restrict__ q,     // [B, 1, D]
    const float* __restrict__ W,     // [D, 2D]
    const float* __restrict__ bias,  // [D]
    float* __restrict__ out)         // d_out, [B, D]
{
    const int d_chunk = blockIdx.x % (DIM / DT);
    const int b_chunk = blockIdx.x / (DIM / DT);
    const int d0 = d_chunk * DT;
    const int b0 = b_chunk * BT;
    const int tid  = threadIdx.x;
    const int wave = tid >> 6;
    const int lane = tid & 63;

    __shared__ float comb[BT * 2 * DIM];   // 4 * 2048 floats = 32 KB
    for (int i = tid; i < BT * 2 * DIM; i += 256) {
        const int bl = i >> 11;          // / 2048
        const int e  = i & 2047;
        comb[i] = (e < DIM) ? mix[(size_t)(b0 + bl) * DIM + e]
                            : q[(size_t)(b0 + bl) * DIM + (e - DIM)];
    }
    __syncthreads();

    const int d_base = d0 + wave * (DT / 4);   // 8 d's per wave
    #pragma unroll
    for (int g = 0; g < 2; ++g) {
        const int dg = d_base + g * 4;
        float acc[4][BT];
        #pragma unroll
        for (int di = 0; di < 4; ++di)
            #pragma unroll
            for (int bl = 0; bl < BT; ++bl) acc[di][bl] = 0.f;

        for (int kk = 0; kk < 2 * DIM; kk += 256) {
            f4_t wv[4];
            #pragma unroll
            for (int di = 0; di < 4; ++di)
                wv[di] = *reinterpret_cast<const f4_t*>(
                    W + (size_t)(dg + di) * (2 * DIM) + kk + lane * 4);
            #pragma unroll
            for (int bl = 0; bl < BT; ++bl) {
                f4_t cv = *reinterpret_cast<const f4_t*>(
                    &comb[bl * 2 * DIM + kk + lane * 4]);
                #pragma unroll
                for (int di = 0; di < 4; ++di) {
                    acc[di][bl] += wv[di].x * cv.x;
                    acc[di][bl] += wv[di].y * cv.y;
                    acc[di][bl] += wv[di].z * cv.z;
                    acc[di][bl] += wv[di].w * cv.w;
                }
            }
        }

        float myval = 0.f;
        #pragma unroll
        for (int di = 0; di < 4; ++di) {
            #pragma unroll
            for (int bl = 0; bl < BT; ++bl) {
                float v = acc[di][bl];
                #pragma unroll
                for (int off = 32; off >= 1; off >>= 1)
                    v += __shfl_xor(v, off, 64);
                if (lane == di * BT + bl) myval = v;
            }
        }
        if (lane < 16) {
            const int di = lane >> 2;
            const int bl = lane & 3;
            const int d  = dg + di;
            out[(size_t)(b0 + bl) * DIM + d] = tanhf(myval + bias[d]);
        }
    }
}

extern "C" void kernel_launch(void* const* d_in, const int* in_sizes, int n_in,
                              void* d_out, int out_size, void* d_ws, size_t ws_size,
                              hipStream_t stream) {
    const float* q    = (const float*)d_in[0];   // output, [B,1,D]
    const float* ctx  = (const float*)d_in[1];   // context, [B,N,D]
    const float* W    = (const float*)d_in[2];   // W_out, [D, 2D]
    const float* bias = (const float*)d_in[3];   // b_out, [D]

    float* out_main = (float*)d_out;                         // [B, D]
    float* attn_out = (float*)d_out + (size_t)BATCH * DIM;   // [B, N]

    // workspace layout (floats): scores | part_m | part_l | part_o | mix  (~5 MB)
    float* ws      = (float*)d_ws;
    float* scores  = ws;                                    // B*N       = 131072
    float* part_m  = scores + (size_t)BATCH * NCTX;         // B*CHUNKS  = 1024
    float* part_l  = part_m + BATCH * CHUNKS;               // 1024
    float* part_o  = part_l + BATCH * CHUNKS;               // B*CHUNKS*D = 1048576
    float* mix     = part_o + (size_t)BATCH * CHUNKS * DIM; // B*D = 65536

    attn_phase1<<<BATCH * CHUNKS, 256, 0, stream>>>(q, ctx, scores,
                                                    part_m, part_l, part_o);
    attn_phase2<<<BATCH * 4, 256, 0, stream>>>(scores, part_m, part_l, part_o,
                                               mix, attn_out);
    attn_phase3<<<(DIM / DT) * (BATCH / BT), 256, 0, stream>>>(mix, q, W, bias,
                                                               out_main);
}